// Round 6
// baseline (283.005 us; speedup 1.0000x reference)
//
#include <hip/hip_runtime.h>
#include <stdint.h>

// ksparse: per row of 4096x8192 f32, threshold = 513th largest (k=512),
// out = x * (x > thresh). Exact radix-select on the order-preserving uint32
// mapping: ONE 11-bit/2048-bin histogram pass, candidate compaction
// (~220 survivors), three 7-bit tail passes in wave 0.
//
// v6b = v6 with the raw barrier hardened. v6 theory: break the
// load->select->store convoy with the T3/T4 pattern (m201): RAW
// __builtin_amdgcn_s_barrier() + "s_waitcnt lgkmcnt(0)" instead of
// __syncthreads() -- the HIP compiler emits s_waitcnt vmcnt(0) before every
// __syncthreads barrier, which killed v2's pipeline. With raw barriers the
// compiler's fine-grained vmcnt counting waits ONLY for the current row's
// loads at their first use, so the NEXT row's loads stay in flight through
// the entire select phase (the ~2.5us wave0 latency chain that left HBM
// idle: 84us measured vs 43.7us pure-HBM floor per CU).
//
// HARDENING (v6b): __builtin_amdgcn_s_barrier() is NOT a compiler memory
// fence (unlike __syncthreads = fence+barrier+fence). v6 only clobbered
// memory BEFORE the barrier, so the compiler could sink the next row's LDS
// zeroing (aliases cand!) above B5 while wave0 still reads cand -> race.
// bar_lds now brackets the barrier with "memory" clobbers on BOTH sides.
//
// Each block pipelines RPB=4 rows with double-buffered row registers
// (fully unrolled -> static indexing, no scratch). 1024 blocks = 4/CU, all
// resident at ~112 VGPR. Select structure is v5's (harness-verified twice):
// wave0 scan + wave0 tails, bin11 identity, float-compare epilogue.

constexpr int COLS  = 8192;
constexpr int TPB   = 256;
constexpr int EPT   = COLS / TPB;   // 32 elements per thread per row
constexpr int VPT   = EPT / 4;      // 8 float4 per thread per row
constexpr int NBIN0 = 2048;         // pass-0 bins (11 bits)
constexpr int CAP   = 2048;         // candidate buffer (reuses replica 1)

__device__ __forceinline__ uint32_t map_f32(uint32_t u) {
  return (u & 0x80000000u) ? ~u : (u | 0x80000000u);
}
__device__ __forceinline__ float unmap_f32(uint32_t m) {
  return __uint_as_float((m & 0x80000000u) ? (m ^ 0x80000000u) : ~m);
}
// Top-11 bits of map_f32(u), without materializing the map:
// positive: (u>>21)|0x400 ; negative: 0x7FF ^ (u>>21).
__device__ __forceinline__ uint32_t bin11(uint32_t u) {
  const uint32_t s = u >> 21;
  return (u & 0x80000000u) ? (0x7FFu ^ s) : (s | 0x400u);
}
// Word-index swizzle within a 2048-bin replica: XOR quad-index bits (2..4)
// with lane bits (5..7). Bijective, preserves 16B alignment; makes wave0's
// 32-bins/lane scan reads conflict-free.
__device__ __forceinline__ uint32_t hswz(uint32_t w) {
  return w ^ ((w >> 3) & 0x1Cu);
}

// Workgroup barrier WITHOUT the vmcnt(0) drain __syncthreads carries.
// lgkmcnt(0) makes this wave's LDS writes/atomics visible before the barrier;
// vmem (next row's in-flight loads + previous row's stores) is untouched.
// Memory clobbers on BOTH sides: the barrier intrinsic alone is not a
// compiler fence, and post-barrier LDS ops must not be hoisted above it.
__device__ __forceinline__ void bar_lds() {
  asm volatile("s_waitcnt lgkmcnt(0)" ::: "memory");
  __builtin_amdgcn_s_barrier();
  asm volatile("" ::: "memory");
}

template <int RPB>
__global__ __launch_bounds__(TPB, 4)
void ksparse_kernel(const float* __restrict__ in, const int* __restrict__ kptr,
                    float* __restrict__ out) {
  __shared__ __align__(16) uint32_t hist[2 * NBIN0]; // 16KB: rep0 | rep1 (-> cand)
  __shared__ uint32_t th[3 * 128];                   // tail histograms
  __shared__ uint32_t s_packed;                      // (d0<<14)|above from pass 0
  __shared__ uint32_t s_cnt;                         // candidate count
  __shared__ uint32_t s_T;                           // final mapped threshold

  const int t    = threadIdx.x;
  const int wave = t >> 6;
  const int lane = t & 63;
  const size_t row0 = (size_t)blockIdx.x * RPB;

  const uint32_t kbase = (uint32_t)(*kptr) + 1u; // rank from top: 513th largest

  float4 v[2][VPT]; // double-buffered row data; loop fully unrolled -> static idx

  // ---- prologue: issue row 0 loads ----
  {
    const float4* inp = (const float4*)(in + row0 * COLS);
#pragma unroll
    for (int i = 0; i < VPT; ++i) v[0][i] = inp[t + i * TPB];
  }

#pragma unroll
  for (int r = 0; r < RPB; ++r) {
    const int cb = r & 1;

    // ---- issue NEXT row's loads first: they stay in flight through all five
    // raw barriers below (no vmcnt drain) and land during this row's select ----
    if (r + 1 < RPB) {
      const float4* inp = (const float4*)(in + (row0 + (size_t)(r + 1)) * COLS);
#pragma unroll
      for (int i = 0; i < VPT; ++i) v[cb ^ 1][i] = inp[t + i * TPB];
    }

    // ---- zero LDS (dead since previous row's B5) ----
    uint4* h4 = (uint4*)hist;
#pragma unroll
    for (int i = 0; i < (2 * NBIN0 / 4) / TPB; ++i) // 4 x 16B per thread
      h4[t + i * TPB] = make_uint4(0u, 0u, 0u, 0u);
    th[t] = 0u;
    if (t < 128) th[256 + t] = 0u;
    if (t == 0) { s_packed = 0u; s_cnt = 0u; }
    bar_lds(); // B1: zeroing visible

    // ---- pass 0: histogram from current row's registers. Compiler inserts a
    // counted vmcnt here (waits row r's loads; row r+1's newer ops remain) ----
    uint32_t* h = &hist[(wave >> 1) * NBIN0]; // waves 0-1 -> rep0, 2-3 -> rep1
#pragma unroll
    for (int i = 0; i < VPT; ++i) {
      atomicAdd(&h[hswz(bin11(__float_as_uint(v[cb][i].x)))], 1u);
      atomicAdd(&h[hswz(bin11(__float_as_uint(v[cb][i].y)))], 1u);
      atomicAdd(&h[hswz(bin11(__float_as_uint(v[cb][i].z)))], 1u);
      atomicAdd(&h[hswz(bin11(__float_as_uint(v[cb][i].w)))], 1u);
    }
    bar_lds(); // B2: histogram visible

    // ---- pass-0 scan in wave 0: lane owns bins [32*lane, 32*lane+32) ----
    if (wave == 0) {
      const uint4* r0 = (const uint4*)&hist[0];
      const uint4* r1 = (const uint4*)&hist[NBIN0];
      uint32_t qs[8]; // per-quad (4-bin) sums
      uint32_t total = 0;
#pragma unroll
      for (int q = 0; q < 8; ++q) {
        const uint32_t Qs = (uint32_t)(8 * lane + q) ^ (uint32_t)(lane & 7);
        const uint4 a = r0[Qs];
        const uint4 b = r1[Qs];
        qs[q] = (a.x + b.x) + (a.y + b.y) + (a.z + b.z) + (a.w + b.w);
        total += qs[q];
      }
      uint32_t s = total; // inclusive suffix over lanes
#pragma unroll
      for (int off = 1; off < 64; off <<= 1) {
        const uint32_t tmp = __shfl_down(s, off, 64);
        s += (lane + off < 64) ? tmp : 0u;
      }
      const unsigned long long mb = __ballot(s >= kbase);
      const int lstar = 63 - __builtin_clzll(mb);
      if (lane == lstar) {
        uint32_t run = s - total; // count in bins above my range
        int qq = -1; uint32_t qab = 0;
#pragma unroll
        for (int q = 7; q >= 0; --q) {
          const uint32_t nrun = run + qs[q];
          if (qq < 0 && nrun >= kbase) { qq = q; qab = run; }
          run = nrun;
        }
        const uint32_t Qs = (uint32_t)(8 * lane + qq) ^ (uint32_t)(lane & 7);
        const uint4 a = r0[Qs];
        const uint4 b = r1[Qs];
        const uint32_t c1 = a.y + b.y, c2 = a.z + b.z, c3 = a.w + b.w;
        const uint32_t s3 = qab + c3;
        const uint32_t s2 = s3 + c2, s1 = s2 + c1;
        uint32_t e, above;
        if (s3 >= kbase)      { e = 3u; above = qab; }
        else if (s2 >= kbase) { e = 2u; above = s3; }
        else if (s1 >= kbase) { e = 1u; above = s2; }
        else                  { e = 0u; above = s1; }
        const uint32_t d0 = (uint32_t)(lane * 32 + qq * 4) + e;
        s_packed = (d0 << 14) | above; // above < kbase <= 16383, fits 14 bits
      }
    }
    bar_lds(); // B3: d0 published

    const uint32_t pk = s_packed;
    const uint32_t d0 = pk >> 14;

    // ---- compact candidates (bin == d0) into dead replica-1 LDS ----
    uint32_t* cand = &hist[NBIN0];
#pragma unroll
    for (int i = 0; i < VPT; ++i) {
      uint32_t u;
      u = __float_as_uint(v[cb][i].x);
      if (bin11(u) == d0) { const uint32_t x = atomicAdd(&s_cnt, 1u); if (x < CAP) cand[x] = map_f32(u) & 0x1FFFFFu; }
      u = __float_as_uint(v[cb][i].y);
      if (bin11(u) == d0) { const uint32_t x = atomicAdd(&s_cnt, 1u); if (x < CAP) cand[x] = map_f32(u) & 0x1FFFFFu; }
      u = __float_as_uint(v[cb][i].z);
      if (bin11(u) == d0) { const uint32_t x = atomicAdd(&s_cnt, 1u); if (x < CAP) cand[x] = map_f32(u) & 0x1FFFFFu; }
      u = __float_as_uint(v[cb][i].w);
      if (bin11(u) == d0) { const uint32_t x = atomicAdd(&s_cnt, 1u); if (x < CAP) cand[x] = map_f32(u) & 0x1FFFFFu; }
    }
    bar_lds(); // B4: compaction done

    // ---- three 7-bit tail passes, entirely in wave 0 ----
    if (wave == 0) {
      const uint32_t Cc = (s_cnt < (uint32_t)CAP) ? s_cnt : (uint32_t)CAP;
      uint32_t kk = kbase - (pk & 0x3FFFu);
      uint32_t tpref = 0;
#pragma unroll 1
      for (int j = 0; j < 3; ++j) {
        const int dsh = 14 - 7 * j;
        uint32_t* thj = &th[j * 128];
        for (uint32_t idx = (uint32_t)lane; idx < Cc; idx += 64u) {
          const uint32_t c = cand[idx];
          const bool ok = (j == 0) || ((c >> (dsh + 7)) == tpref);
          if (ok) atomicAdd(&thj[(c >> dsh) & 127u], 1u);
        }
        const uint32_t a = thj[lane], b = thj[64 + lane];
        uint32_t sb = b, sa = a;
#pragma unroll
        for (int off = 1; off < 64; off <<= 1) {
          const uint32_t t1 = __shfl_down(sb, off, 64);
          const uint32_t t2 = __shfl_down(sa, off, 64);
          const bool inr = (lane + off < 64);
          sb += inr ? t1 : 0u;
          sa += inr ? t2 : 0u;
        }
        const uint32_t tb = __shfl(sb, 0, 64); // total of bins 64..127
        sa += tb;
        const unsigned long long mbj = __ballot(sb >= kk);
        uint32_t d, ab;
        if (mbj) {
          const int hb = 63 - __builtin_clzll(mbj);
          const uint32_t nx = __shfl(sb, (hb + 1) & 63, 64);
          d = 64u + (uint32_t)hb;
          ab = (hb == 63) ? 0u : nx;
        } else {
          const unsigned long long ma = __ballot(sa >= kk); // nonzero by invariant
          const int ha = 63 - __builtin_clzll(ma);
          const uint32_t nx = __shfl(sa, (ha + 1) & 63, 64);
          d = (uint32_t)ha;
          ab = (ha == 63) ? tb : nx;
        }
        tpref = (tpref << 7) | d;
        kk -= ab;
      }
      if (lane == 0) s_T = (d0 << 21) | tpref; // exact mapped bits of rank-(k+1)
    }
    bar_lds(); // B5: threshold published

    // ---- masked write with FLOAT compare (== reference's strict >).
    // Stores overlap the next row's zero/histogram phases. ----
    const float thr = unmap_f32(s_T);
    float4* op = (float4*)(out + (row0 + (size_t)r) * COLS);
#pragma unroll
    for (int i = 0; i < VPT; ++i) {
      float4 w;
      w.x = (v[cb][i].x > thr) ? v[cb][i].x : 0.0f;
      w.y = (v[cb][i].y > thr) ? v[cb][i].y : 0.0f;
      w.z = (v[cb][i].z > thr) ? v[cb][i].z : 0.0f;
      w.w = (v[cb][i].w > thr) ? v[cb][i].w : 0.0f;
      op[t + i * TPB] = w;
    }
  }
}

extern "C" void kernel_launch(void* const* d_in, const int* in_sizes, int n_in,
                              void* d_out, int out_size, void* d_ws, size_t ws_size,
                              hipStream_t stream) {
  const float* in  = (const float*)d_in[0];
  const int*   k   = (const int*)d_in[1];
  float*       out = (float*)d_out;
  int rows = in_sizes[0] / COLS;
  if (rows < 1) rows = 1;
  if ((rows & 3) == 0) {
    ksparse_kernel<4><<<rows / 4, TPB, 0, stream>>>(in, k, out);
  } else {
    ksparse_kernel<1><<<rows, TPB, 0, stream>>>(in, k, out);
  }
}

// Round 7
// 262.364 us; speedup vs baseline: 1.0787x; 1.0787x over previous
//
#include <hip/hip_runtime.h>
#include <stdint.h>

// ksparse: per row of 4096x8192 f32, threshold = 513th largest (k=512),
// out = x * (x > thresh). Exact radix-select on the order-preserving uint32
// mapping: ONE 11-bit/2048-bin histogram pass, candidate compaction
// (~220 survivors), three 7-bit tail passes in wave 0 (v5 select structure,
// harness-verified 3x).
//
// v7: cross-row pipeline WITHOUT register double-buffering (v3/v6b spilled;
// reg dbuf is un-affordable) -- prefetch the next row into a single 32KB LDS
// staging buffer via __builtin_amdgcn_global_load_lds (async DMA, zero VGPR
// cost). Per-wave quarter ownership: wave w DMAs and reads ONLY its own 8KB
// quarter, so all staging hazards are intra-wave and the raw bar_lds
// barriers (no vmcnt drain; proven safe in v6b) never touch the staging
// stream. Steady-state per row:
//   fused {ds_read quarter -> v[8] + histogram}        (row r)
//   lgkmcnt(0); issue 8x global_load_lds               (row r+1 DMA)
//   B2..B5 select + 8x global_store                    (row r, ~2.5us)
//   s_waitcnt vmcnt(8)  <- drains [ST(r-1), DMA(r+1)], keeps ST(r) in flight
// The DMA streams under the whole select phase: HBM never idles.
// No __launch_bounds__ min-waves arg: (256,4) made hipcc clamp to 64 VGPR
// and spill (v3: 137MB, v6b: 202MB writes). Demand here = v1's ~48-56.
// LDS = 16K hist + 32K stage + 1.5K th ~= 50KB -> 3 blocks/CU.

constexpr int COLS  = 8192;
constexpr int TPB   = 256;
constexpr int VPT   = 8;            // float4 per thread per row
constexpr int NBIN0 = 2048;         // pass-0 bins (11 bits)
constexpr int CAP   = 2048;         // candidate buffer (reuses replica 1)

__device__ __forceinline__ uint32_t map_f32(uint32_t u) {
  return (u & 0x80000000u) ? ~u : (u | 0x80000000u);
}
__device__ __forceinline__ float unmap_f32(uint32_t m) {
  return __uint_as_float((m & 0x80000000u) ? (m ^ 0x80000000u) : ~m);
}
// Top-11 bits of map_f32(u): positive: (u>>21)|0x400 ; negative: 0x7FF^(u>>21).
__device__ __forceinline__ uint32_t bin11(uint32_t u) {
  const uint32_t s = u >> 21;
  return (u & 0x80000000u) ? (0x7FFu ^ s) : (s | 0x400u);
}
// Word-index swizzle within a 2048-bin replica: XOR quad bits (2..4) with
// lane bits (5..7). Bijective; wave0's 32-bins/lane scan reads conflict-free.
__device__ __forceinline__ uint32_t hswz(uint32_t w) {
  return w ^ ((w >> 3) & 0x1Cu);
}

// Workgroup barrier WITHOUT __syncthreads' vmcnt(0) drain. lgkmcnt(0) makes
// LDS writes visible; memory clobbers on BOTH sides (barrier intrinsic is
// not a compiler fence -- v6b hardening, correctness-verified).
__device__ __forceinline__ void bar_lds() {
  asm volatile("s_waitcnt lgkmcnt(0)" ::: "memory");
  __builtin_amdgcn_s_barrier();
  asm volatile("" ::: "memory");
}

// Async 16B-wide global->LDS DMA. lds base wave-uniform + lane*16 (HW rule);
// global source per-lane.
__device__ __forceinline__ void gl2lds16(const float* g, float* l) {
  __builtin_amdgcn_global_load_lds(
      (const __attribute__((address_space(1))) void*)g,
      (__attribute__((address_space(3))) void*)l, 16, 0, 0);
}

// Wave w stages its 8KB quarter of a 32KB row: 8 instructions x 1KB.
__device__ __forceinline__ void stage_row(const float* __restrict__ rowp,
                                          float* stage, int wave, int lane) {
  const float* g = rowp + (wave << 11) + (lane << 2); // wave*2048 + lane*4 floats
  float* l = stage + (wave << 11);                    // wave-uniform base
#pragma unroll
  for (int i = 0; i < VPT; ++i)
    gl2lds16(g + i * 256, l + i * 256);               // +1KB per step
}

template <int RPB>
__global__ __launch_bounds__(TPB)
void ksparse_kernel(const float* __restrict__ in, const int* __restrict__ kptr,
                    float* __restrict__ out) {
  __shared__ __align__(16) uint32_t hist[2 * NBIN0]; // 16KB: rep0 | rep1 (-> cand)
  __shared__ __align__(16) float    stage[COLS];     // 32KB row staging (per-wave quarters)
  __shared__ uint32_t th[3 * 128];                   // tail histograms
  __shared__ uint32_t s_packed;                      // (d0<<14)|above from pass 0
  __shared__ uint32_t s_cnt;                         // candidate count
  __shared__ uint32_t s_T;                           // final mapped threshold

  const int t    = threadIdx.x;
  const int wave = t >> 6;
  const int lane = t & 63;
  const size_t row0 = (size_t)blockIdx.x * RPB;

  const uint32_t kbase = (uint32_t)(*kptr) + 1u; // s_load (lgkm), not vmem

  // ---- prologue: DMA row 0 into the staging buffer ----
  stage_row(in + row0 * COLS, stage, wave, lane);

#pragma unroll
  for (int r = 0; r < RPB; ++r) {
    // ---- zero LDS (hist/th dead since previous row's B5); overlaps DMA ----
    uint4* h4 = (uint4*)hist;
#pragma unroll
    for (int i = 0; i < 4; ++i) // 2*2048 words = 1024 uint4 / 256 thr
      h4[t + i * TPB] = make_uint4(0u, 0u, 0u, 0u);
    th[t] = 0u;
    if (t < 128) th[256 + t] = 0u;
    if (t == 0) { s_packed = 0u; s_cnt = 0u; }
    bar_lds(); // B1

    if (r == 0) asm volatile("s_waitcnt vmcnt(0)" ::: "memory"); // row0 DMA only

    // ---- fused LDS->reg + histogram: wave reads its OWN quarter ----
    float4 v[VPT];
    uint32_t* h = &hist[(wave >> 1) * NBIN0]; // waves 0-1 -> rep0, 2-3 -> rep1
    const float4* sq = (const float4*)stage + (wave << 9) + lane;
#pragma unroll
    for (int i = 0; i < VPT; ++i) {
      v[i] = sq[i << 6]; // i*64 float4 = +1KB
      atomicAdd(&h[hswz(bin11(__float_as_uint(v[i].x)))], 1u);
      atomicAdd(&h[hswz(bin11(__float_as_uint(v[i].y)))], 1u);
      atomicAdd(&h[hswz(bin11(__float_as_uint(v[i].z)))], 1u);
      atomicAdd(&h[hswz(bin11(__float_as_uint(v[i].w)))], 1u);
    }
    // my quarter is consumed -> start next row's DMA into it; streams under
    // the whole select phase below.
    if (r + 1 < RPB) {
      asm volatile("s_waitcnt lgkmcnt(0)" ::: "memory"); // my ds_reads done
      stage_row(in + (row0 + (size_t)(r + 1)) * COLS, stage, wave, lane);
    }
    bar_lds(); // B2: histogram visible

    // ---- pass-0 scan in wave 0: lane owns bins [32*lane, 32*lane+32) ----
    if (wave == 0) {
      const uint4* r0 = (const uint4*)&hist[0];
      const uint4* r1 = (const uint4*)&hist[NBIN0];
      uint32_t qs[8];
      uint32_t total = 0;
#pragma unroll
      for (int q = 0; q < 8; ++q) {
        const uint32_t Qs = (uint32_t)(8 * lane + q) ^ (uint32_t)(lane & 7);
        const uint4 a = r0[Qs];
        const uint4 b = r1[Qs];
        qs[q] = (a.x + b.x) + (a.y + b.y) + (a.z + b.z) + (a.w + b.w);
        total += qs[q];
      }
      uint32_t s = total; // inclusive suffix over lanes
#pragma unroll
      for (int off = 1; off < 64; off <<= 1) {
        const uint32_t tmp = __shfl_down(s, off, 64);
        s += (lane + off < 64) ? tmp : 0u;
      }
      const unsigned long long mb = __ballot(s >= kbase);
      const int lstar = 63 - __builtin_clzll(mb);
      if (lane == lstar) {
        uint32_t run = s - total;
        int qq = -1; uint32_t qab = 0;
#pragma unroll
        for (int q = 7; q >= 0; --q) {
          const uint32_t nrun = run + qs[q];
          if (qq < 0 && nrun >= kbase) { qq = q; qab = run; }
          run = nrun;
        }
        const uint32_t Qs = (uint32_t)(8 * lane + qq) ^ (uint32_t)(lane & 7);
        const uint4 a = r0[Qs];
        const uint4 b = r1[Qs];
        const uint32_t c1 = a.y + b.y, c2 = a.z + b.z, c3 = a.w + b.w;
        const uint32_t s3 = qab + c3;
        const uint32_t s2 = s3 + c2, s1 = s2 + c1;
        uint32_t e, above;
        if (s3 >= kbase)      { e = 3u; above = qab; }
        else if (s2 >= kbase) { e = 2u; above = s3; }
        else if (s1 >= kbase) { e = 1u; above = s2; }
        else                  { e = 0u; above = s1; }
        const uint32_t d0 = (uint32_t)(lane * 32 + qq * 4) + e;
        s_packed = (d0 << 14) | above;
      }
    }
    bar_lds(); // B3: d0 published

    const uint32_t pk = s_packed;
    const uint32_t d0 = pk >> 14;

    // ---- compact candidates (bin == d0) into dead replica-1 LDS ----
    uint32_t* cand = &hist[NBIN0];
#pragma unroll
    for (int i = 0; i < VPT; ++i) {
      uint32_t u;
      u = __float_as_uint(v[i].x);
      if (bin11(u) == d0) { const uint32_t x = atomicAdd(&s_cnt, 1u); if (x < CAP) cand[x] = map_f32(u) & 0x1FFFFFu; }
      u = __float_as_uint(v[i].y);
      if (bin11(u) == d0) { const uint32_t x = atomicAdd(&s_cnt, 1u); if (x < CAP) cand[x] = map_f32(u) & 0x1FFFFFu; }
      u = __float_as_uint(v[i].z);
      if (bin11(u) == d0) { const uint32_t x = atomicAdd(&s_cnt, 1u); if (x < CAP) cand[x] = map_f32(u) & 0x1FFFFFu; }
      u = __float_as_uint(v[i].w);
      if (bin11(u) == d0) { const uint32_t x = atomicAdd(&s_cnt, 1u); if (x < CAP) cand[x] = map_f32(u) & 0x1FFFFFu; }
    }
    bar_lds(); // B4: compaction done

    // ---- three 7-bit tail passes, entirely in wave 0 ----
    if (wave == 0) {
      const uint32_t Cc = (s_cnt < (uint32_t)CAP) ? s_cnt : (uint32_t)CAP;
      uint32_t kk = kbase - (pk & 0x3FFFu);
      uint32_t tpref = 0;
#pragma unroll 1
      for (int j = 0; j < 3; ++j) {
        const int dsh = 14 - 7 * j;
        uint32_t* thj = &th[j * 128];
        for (uint32_t idx = (uint32_t)lane; idx < Cc; idx += 64u) {
          const uint32_t c = cand[idx];
          const bool ok = (j == 0) || ((c >> (dsh + 7)) == tpref);
          if (ok) atomicAdd(&thj[(c >> dsh) & 127u], 1u);
        }
        const uint32_t a = thj[lane], b = thj[64 + lane];
        uint32_t sb = b, sa = a;
#pragma unroll
        for (int off = 1; off < 64; off <<= 1) {
          const uint32_t t1 = __shfl_down(sb, off, 64);
          const uint32_t t2 = __shfl_down(sa, off, 64);
          const bool inr = (lane + off < 64);
          sb += inr ? t1 : 0u;
          sa += inr ? t2 : 0u;
        }
        const uint32_t tb = __shfl(sb, 0, 64); // total of bins 64..127
        sa += tb;
        const unsigned long long mbj = __ballot(sb >= kk);
        uint32_t d, ab;
        if (mbj) {
          const int hb = 63 - __builtin_clzll(mbj);
          const uint32_t nx = __shfl(sb, (hb + 1) & 63, 64);
          d = 64u + (uint32_t)hb;
          ab = (hb == 63) ? 0u : nx;
        } else {
          const unsigned long long ma = __ballot(sa >= kk); // nonzero by invariant
          const int ha = 63 - __builtin_clzll(ma);
          const uint32_t nx = __shfl(sa, (ha + 1) & 63, 64);
          d = (uint32_t)ha;
          ab = (ha == 63) ? tb : nx;
        }
        tpref = (tpref << 7) | d;
        kk -= ab;
      }
      if (lane == 0) s_T = (d0 << 21) | tpref;
    }
    bar_lds(); // B5: threshold published

    // ---- masked write with FLOAT compare (== reference's strict >) ----
    const float thr = unmap_f32(s_T);
    float4* op = (float4*)(out + (row0 + (size_t)r) * COLS) + (wave << 9) + lane;
#pragma unroll
    for (int i = 0; i < VPT; ++i) {
      float4 w;
      w.x = (v[i].x > thr) ? v[i].x : 0.0f;
      w.y = (v[i].y > thr) ? v[i].y : 0.0f;
      w.z = (v[i].z > thr) ? v[i].z : 0.0f;
      w.w = (v[i].w > thr) ? v[i].w : 0.0f;
      op[i << 6] = w;
    }
    // Counted drain (T4: never vmcnt(0) in the loop): outstanding here =
    // [ST(r-1) x8, DMA(r+1) x8, ST(r) x8]; wait to <=8 drains prev stores +
    // next row's DMA (needed by the next iteration's ds_reads), keeps the
    // newest 8 stores in flight under the next row's zero+hist phases.
    asm volatile("s_waitcnt vmcnt(8)" ::: "memory");
  }
}

extern "C" void kernel_launch(void* const* d_in, const int* in_sizes, int n_in,
                              void* d_out, int out_size, void* d_ws, size_t ws_size,
                              hipStream_t stream) {
  const float* in  = (const float*)d_in[0];
  const int*   k   = (const int*)d_in[1];
  float*       out = (float*)d_out;
  int rows = in_sizes[0] / COLS;
  if (rows < 1) rows = 1;
  if ((rows & 3) == 0) {
    ksparse_kernel<4><<<rows / 4, TPB, 0, stream>>>(in, k, out);
  } else {
    ksparse_kernel<1><<<rows, TPB, 0, stream>>>(in, k, out);
  }
}